// Round 13
// baseline (83.172 us; speedup 1.0000x reference)
//
#include <hip/hip_runtime.h>
#include <hip/hip_bf16.h>
#include <math.h>

#define BB 2
#define NN 512
#define KK 128
#define EE 768
#define NUM_EDGES 1536

// -0.5 * log2(e): folds exp(-0.5 u^2) into one exp2
#define CH (-0.7213475204444817f)

// ---------------- single fused kernel: 512 blocks x 512 threads, 2 rows/block ----------------
// stage 0-2: phase A (time-MLP, threads 0..255) OVERLAPPED with phase B (rows'
//            dist/gather, threads 256..511), barrier-aligned.
// phase C:   both rows concurrently (half-block each); per-wave float2 store
//            pattern identical to the proven R4 kernel; 16 waves/CU aggregate.
// phase D:   one proj_w pass serves both rows (L2 traffic halved vs R4).
__global__ __launch_bounds__(512) void edge_fused2_kernel(
    const float* __restrict__ pos,
    const int* __restrict__ node_type_edge,
    const int* __restrict__ padding_mask,
    const int* __restrict__ mask_aa,
    const int* __restrict__ mask_pos,
    const int* __restrict__ time_pos,
    const float* __restrict__ means,
    const float* __restrict__ stds,
    const float* __restrict__ mul_w,
    const float* __restrict__ bias_w,
    const float* __restrict__ proj_w,   // [K,E]
    const float* __restrict__ proj_b,   // [E]
    const float* __restrict__ t_w1, const float* __restrict__ t_b1,
    const float* __restrict__ t_w2, const float* __restrict__ t_b2,
    float* __restrict__ out_ef,    // [B,N,N,K]
    float* __restrict__ out_merge, // [B,N,E]
    float* __restrict__ out_dp)    // [B,N,N,3]
{
    __shared__ float e2[2][KK];
    __shared__ float h2[2][KK];
    __shared__ float tv[2][KK];          // tv[0]=2*t_enc(t_b), tv[1]=2*t_enc(0)
    __shared__ float xv2[2][NN];         // per-row mul*dist+bias
    __shared__ unsigned char fl2[2][NN]; // per-row flags
    __shared__ float red[2 * 4 * KK];    // per-row j-group partials
    __shared__ float sums[2][KK];

    const int bi0 = blockIdx.x * 2;      // first of two rows (same b: bi0 even)
    const int b = bi0 >> 9;
    const int i0 = bi0 & (NN - 1);
    const int tid = threadIdx.x;

    // ---------------- stages 0..2: A (tid<256) || B (tid>=256) ----------------
    // B-thread mapping: bt = tid-256; row r = bt>>7; lane = bt&127; j = lane + q*128
    const int bt   = tid - 256;
    const int brow = (bt >> 7) & 1;
    const int blane = bt & 127;
    const int gbiB = bi0 + brow;

    float pixB = 0.f, piyB = 0.f, pizB = 0.f;
    int maa_iB = 0, mpos_iB = 0;
    if (tid >= 256) {
        const int iB = gbiB & (NN - 1);
        pixB = pos[(b * NN + iB) * 3 + 0];
        piyB = pos[(b * NN + iB) * 3 + 1];
        pizB = pos[(b * NN + iB) * 3 + 2];
        maa_iB  = mask_aa[b * NN + iB];
        mpos_iB = mask_pos[b * NN + iB];
    }

#define B_WORK(q)                                                              \
    {                                                                          \
        const int j = blane + (q) * 128;                                       \
        const float dx = pos[(b * NN + j) * 3 + 0] - pixB;                     \
        const float dy = pos[(b * NN + j) * 3 + 1] - piyB;                     \
        const float dz = pos[(b * NN + j) * 3 + 2] - pizB;                     \
        const float dist = sqrtf(dx * dx + dy * dy + dz * dz);                 \
        const float invd = 1.0f / (dist + 1e-5f);                              \
        const size_t dpo = ((size_t)gbiB * NN + j) * 3;                        \
        out_dp[dpo + 0] = dx * invd;                                           \
        out_dp[dpo + 1] = dy * invd;                                           \
        out_dp[dpo + 2] = dz * invd;                                           \
        const int base = (gbiB * NN + j) * 2;                                  \
        int e0 = node_type_edge[base + 0];                                     \
        int e1 = node_type_edge[base + 1];                                     \
        if (maa_iB)              e0 = 0;                                       \
        if (mask_aa[b * NN + j]) e1 = 0;                                       \
        const float mul  = mul_w[e0]  + mul_w[e1];                             \
        const float bias = bias_w[e0] + bias_w[e1];                            \
        xv2[brow][j] = mul * dist + bias;                                      \
        const int md  = (mpos_iB | mask_pos[b * NN + j]) ? 1 : 0;              \
        const int pad = padding_mask[b * NN + j] ? 2 : 0;                      \
        fl2[brow][j] = (unsigned char)(md | pad);                              \
    }

    const int enc = (tid >> 7) & 1;      // for A threads
    const int ak = tid & 127;

    // stage 0: sinusoidal embedding || B q=0
    if (tid < 256) {
        const float t = (enc == 0) ? (float)time_pos[b] : 0.0f;
        const int kk = ak & 63;
        const float freq = __expf(-logf(10000.0f) * (float)kk * (1.0f / 64.0f));
        const float arg = t * freq;
        e2[enc][ak] = (ak < 64) ? cosf(arg) : sinf(arg);
    } else {
        B_WORK(0)
    }
    __syncthreads();

    // stage 1: layer 1 + SiLU || B q=1
    if (tid < 256) {
        float acc = t_b1[ak];
#pragma unroll 8
        for (int r = 0; r < KK; ++r) acc += e2[enc][r] * t_w1[r * KK + ak];
        h2[enc][ak] = acc / (1.0f + __expf(-acc));
    } else {
        B_WORK(1)
    }
    __syncthreads();

    // stage 2: layer 2 || B q=2,3
    if (tid < 256) {
        float acc2 = t_b2[ak];
#pragma unroll 8
        for (int r = 0; r < KK; ++r) acc2 += h2[enc][r] * t_w2[r * KK + ak];
        tv[enc][ak] = 2.0f * acc2;
    } else {
        B_WORK(2)
        B_WORK(3)
    }
    __syncthreads();

    // ---------------- phase C: both rows concurrently ----------------
    // tid 0..255 -> row 0, tid 256..511 -> row 1; within half: R4-exact layout.
    const int crow = tid >> 8;
    const int ct = tid & 255;
    const int k0 = (ct & 63) * 2;
    const int jg = ct >> 6;              // 0..3 (wave-uniform)
    const float a = sqrtf(2.0f * 3.14159f);

    const float mean0 = means[k0];
    const float mean1 = means[k0 + 1];
    const float sd0 = fabsf(stds[k0]) + 0.01f;
    const float sd1 = fabsf(stds[k0 + 1]) + 0.01f;
    const float inv0 = 1.0f / sd0, inv1 = 1.0f / sd1;
    const float nmi0 = -mean0 * inv0, nmi1 = -mean1 * inv1;
    const float coef0 = 1.0f / (a * sd0), coef1 = 1.0f / (a * sd1);
    const float t2_0  = tv[0][k0];
    const float t2_1  = tv[0][k0 + 1];
    const float t02_0 = tv[1][k0];
    const float t02_1 = tv[1][k0 + 1];

    float s0 = 0.0f, s1 = 0.0f;
    const size_t efbase = (size_t)(bi0 + crow) * NN * KK;
    const float* __restrict__ xvr = xv2[crow];
    const unsigned char* __restrict__ flr = fl2[crow];

    for (int jj = 0; jj < NN / 4; ++jj) {
        const int j = jj * 4 + jg;
        const float x = xvr[j];
        const unsigned char f = flr[j];
        const float ts0 = (f & 1) ? t2_0 : t02_0;
        const float ts1 = (f & 1) ? t2_1 : t02_1;

        const float u0 = __builtin_fmaf(x, inv0, nmi0);
        const float u1 = __builtin_fmaf(x, inv1, nmi1);
        const float g0 = __builtin_exp2f((u0 * CH) * u0);
        const float g1 = __builtin_exp2f((u1 * CH) * u1);
        float v0 = __builtin_fmaf(g0, coef0, ts0);
        float v1 = __builtin_fmaf(g1, coef1, ts1);
        if (f & 2) { v0 = 0.0f; v1 = 0.0f; }
        s0 += v0; s1 += v1;

        float2 pack; pack.x = v0; pack.y = v1;
        *reinterpret_cast<float2*>(&out_ef[efbase + (size_t)j * KK + k0]) = pack;
    }

    red[crow * 4 * KK + jg * KK + k0]     = s0;
    red[crow * 4 * KK + jg * KK + k0 + 1] = s1;
    __syncthreads();

    // reduce: threads 0..127 -> row0, 128..255 -> row1
    if (tid < 256) {
        const int r = tid >> 7;
        const int k = tid & 127;
        const float* rr = &red[r * 4 * KK];
        sums[r][k] = rr[k] + rr[KK + k] + rr[2 * KK + k] + rr[3 * KK + k];
    }
    __syncthreads();

    // ---------------- phase D: one proj_w pass for both rows ----------------
    // e-col coverage: all 512 threads own e=tid; threads 0..255 also e=512+tid.
    const int pad0 = padding_mask[b * NN + i0];
    const int pad1 = padding_mask[b * NN + i0 + 1];

    float a00 = 0.f, a01 = 0.f, a10 = 0.f, a11 = 0.f;
    const bool two = (tid < 256);
#pragma unroll 8
    for (int k = 0; k < KK; ++k) {
        const float s0k = sums[0][k];
        const float s1k = sums[1][k];
        const float w0 = proj_w[k * EE + tid];
        a00 += s0k * w0;
        a01 += s1k * w0;
        if (two) {
            const float w1 = proj_w[k * EE + 512 + tid];
            a10 += s0k * w1;
            a11 += s1k * w1;
        }
    }

    {
        const float pb0 = proj_b[tid];
        const size_t o0 = (size_t)bi0 * EE;
        const size_t o1 = (size_t)(bi0 + 1) * EE;
        out_merge[o0 + tid] = pad0 ? 0.0f : (a00 + pb0);
        out_merge[o1 + tid] = pad1 ? 0.0f : (a01 + pb0);
        if (two) {
            const float pb1 = proj_b[512 + tid];
            out_merge[o0 + 512 + tid] = pad0 ? 0.0f : (a10 + pb1);
            out_merge[o1 + 512 + tid] = pad1 ? 0.0f : (a11 + pb1);
        }
    }
}

extern "C" void kernel_launch(void* const* d_in, const int* in_sizes, int n_in,
                              void* d_out, int out_size, void* d_ws, size_t ws_size,
                              hipStream_t stream) {
    const float* pos          = (const float*)d_in[0];
    const int* node_type_edge = (const int*)d_in[1];
    const int* padding_mask   = (const int*)d_in[2];
    const int* mask_aa        = (const int*)d_in[3];
    const int* mask_pos       = (const int*)d_in[4];
    const int* time_pos      = (const int*)d_in[5];
    const float* means        = (const float*)d_in[6];
    const float* stds         = (const float*)d_in[7];
    const float* mul_w        = (const float*)d_in[8];
    const float* bias_w       = (const float*)d_in[9];
    const float* proj_w       = (const float*)d_in[10];
    const float* proj_b       = (const float*)d_in[11];
    const float* t_w1         = (const float*)d_in[12];
    const float* t_b1         = (const float*)d_in[13];
    const float* t_w2         = (const float*)d_in[14];
    const float* t_b2         = (const float*)d_in[15];

    float* out       = (float*)d_out;
    float* out_ef    = out;                                        // B*N*N*K
    float* out_merge = out + (size_t)BB * NN * NN * KK;            // B*N*E
    float* out_dp    = out_merge + (size_t)BB * NN * EE;           // B*N*N*3

    edge_fused2_kernel<<<(BB * NN) / 2, 512, 0, stream>>>(
        pos, node_type_edge, padding_mask, mask_aa, mask_pos, time_pos,
        means, stds, mul_w, bias_w, proj_w, proj_b,
        t_w1, t_b1, t_w2, t_b2,
        out_ef, out_merge, out_dp);
}

// Round 14
// 59.781 us; speedup vs baseline: 1.3913x; 1.3913x over previous
//
#include <hip/hip_runtime.h>
#include <hip/hip_bf16.h>
#include <math.h>

#define BB 2
#define NN 512
#define KK 128
#define EE 768
#define NUM_EDGES 1536
#define RPB 4   // rows per block; grid = B*N/RPB = 256 blocks x 1024 threads

// ---------------- single fused kernel: 4 rows per 1024-thread block ----------------
// A: R4-exact time-MLP on threads 0..255 (others wait; latency-bound anyway)
// B: group g (256 threads) = row g, per-thread code R4-exact
// C: group g = row g, R4-exact float2 stores (per-wave pattern unchanged)
// D: ONE proj_w pass serves all 4 rows (W L2 traffic 402 MB -> 100 MB)
__global__ __launch_bounds__(1024) void edge_fused4_kernel(
    const float* __restrict__ pos,
    const int* __restrict__ node_type_edge,
    const int* __restrict__ padding_mask,
    const int* __restrict__ mask_aa,
    const int* __restrict__ mask_pos,
    const int* __restrict__ time_pos,
    const float* __restrict__ means,
    const float* __restrict__ stds,
    const float* __restrict__ mul_w,
    const float* __restrict__ bias_w,
    const float* __restrict__ proj_w,   // [K,E]
    const float* __restrict__ proj_b,   // [E]
    const float* __restrict__ t_w1, const float* __restrict__ t_b1,
    const float* __restrict__ t_w2, const float* __restrict__ t_b2,
    float* __restrict__ out_ef,    // [B,N,N,K]
    float* __restrict__ out_merge, // [B,N,E]
    float* __restrict__ out_dp)    // [B,N,N,3]
{
    __shared__ float e2[2][KK];
    __shared__ float h2[2][KK];
    __shared__ float tv[2][KK];            // tv[0]=2*t_enc(t_b), tv[1]=2*t_enc(0)
    __shared__ float xv[RPB][NN];          // per-row mul*dist+bias (8 KB)
    __shared__ unsigned char fl[RPB][NN];  // per-row flags (2 KB)
    __shared__ float red[RPB][4 * KK];     // per-row j-group partials (8 KB)
    __shared__ float sums[RPB][KK];        // per-row k-sums (2 KB)
    __shared__ int padr[RPB];

    const int bi0 = blockIdx.x * RPB;      // 4 rows, same b (512 % 4 == 0)
    const int b = bi0 >> 9;
    const int tid = threadIdx.x;
    const int grp = tid >> 8;              // 0..3 : row group
    const int gt  = tid & 255;             // thread-in-group (R4's "tid")
    const int bi  = bi0 + grp;
    const int i   = bi & (NN - 1);

    // ---- phase A (threads 0..255, R4-exact; other groups wait at barrier) ----
    if (grp == 0) {
        const int enc = gt >> 7;
        const int k = gt & 127;
        const float t = (enc == 0) ? (float)time_pos[b] : 0.0f;
        const int kk = k & 63;
        const float freq = __expf(-logf(10000.0f) * (float)kk * (1.0f / 64.0f));
        const float arg = t * freq;
        e2[enc][k] = (k < 64) ? cosf(arg) : sinf(arg);
    }
    __syncthreads();
    if (grp == 0) {
        const int enc = gt >> 7;
        const int k = gt & 127;
        float acc = t_b1[k];
#pragma unroll 8
        for (int r = 0; r < KK; ++r) acc += e2[enc][r] * t_w1[r * KK + k];
        h2[enc][k] = acc / (1.0f + __expf(-acc));
    }
    __syncthreads();
    if (grp == 0) {
        const int enc = gt >> 7;
        const int k = gt & 127;
        float acc2 = t_b2[k];
#pragma unroll 8
        for (int r = 0; r < KK; ++r) acc2 += h2[enc][r] * t_w2[r * KK + k];
        tv[enc][k] = 2.0f * acc2;
    }

    // ---- phase B: group g handles row g (R4-exact per-thread work) ----
    const float pix = pos[(b * NN + i) * 3 + 0];
    const float piy = pos[(b * NN + i) * 3 + 1];
    const float piz = pos[(b * NN + i) * 3 + 2];
    const int maa_i  = mask_aa[b * NN + i];
    const int mpos_i = mask_pos[b * NN + i];

    for (int j = gt; j < NN; j += 256) {
        const float dx = pos[(b * NN + j) * 3 + 0] - pix;
        const float dy = pos[(b * NN + j) * 3 + 1] - piy;
        const float dz = pos[(b * NN + j) * 3 + 2] - piz;
        const float dist = sqrtf(dx * dx + dy * dy + dz * dz);
        const float invd = 1.0f / (dist + 1e-5f);
        const size_t dpo = ((size_t)bi * NN + j) * 3;
        out_dp[dpo + 0] = dx * invd;
        out_dp[dpo + 1] = dy * invd;
        out_dp[dpo + 2] = dz * invd;

        const int base = (bi * NN + j) * 2;
        int e0 = node_type_edge[base + 0];
        int e1 = node_type_edge[base + 1];
        if (maa_i)               e0 = 0;
        if (mask_aa[b * NN + j]) e1 = 0;
        const float mul  = mul_w[e0]  + mul_w[e1];
        const float bias = bias_w[e0] + bias_w[e1];
        xv[grp][j] = mul * dist + bias;

        const int md  = (mpos_i | mask_pos[b * NN + j]) ? 1 : 0;
        const int pad = padding_mask[b * NN + j] ? 2 : 0;
        fl[grp][j] = (unsigned char)(md | pad);
    }
    if (gt == 0) padr[grp] = padding_mask[b * NN + i];
    __syncthreads();   // tv/xv/fl visible

    // ---- phase C: group g = row g; R4-exact (2 k/thread, 4 j-groups, float2) ----
    const int k0 = (gt & 63) * 2;
    const int jg = gt >> 6;
    const float a = sqrtf(2.0f * 3.14159f);

    const float mean0 = means[k0];
    const float mean1 = means[k0 + 1];
    const float sd0 = fabsf(stds[k0]) + 0.01f;
    const float sd1 = fabsf(stds[k0 + 1]) + 0.01f;
    const float inv0 = 1.0f / sd0, inv1 = 1.0f / sd1;
    const float coef0 = 1.0f / (a * sd0), coef1 = 1.0f / (a * sd1);
    const float t2_0  = tv[0][k0];
    const float t2_1  = tv[0][k0 + 1];
    const float t02_0 = tv[1][k0];
    const float t02_1 = tv[1][k0 + 1];

    float s0 = 0.0f, s1 = 0.0f;
    const size_t efbase = (size_t)bi * NN * KK;
    const float* __restrict__ xvr = xv[grp];
    const unsigned char* __restrict__ flr = fl[grp];

    for (int jj = 0; jj < NN / 4; ++jj) {
        const int j = jj * 4 + jg;
        const float x = xvr[j];
        const unsigned char f = flr[j];

        const float u0 = (x - mean0) * inv0;
        const float u1 = (x - mean1) * inv1;
        float v0 = __expf(-0.5f * u0 * u0) * coef0 + ((f & 1) ? t2_0 : t02_0);
        float v1 = __expf(-0.5f * u1 * u1) * coef1 + ((f & 1) ? t2_1 : t02_1);
        if (f & 2) { v0 = 0.0f; v1 = 0.0f; }
        s0 += v0; s1 += v1;

        float2 pack; pack.x = v0; pack.y = v1;
        *reinterpret_cast<float2*>(&out_ef[efbase + (size_t)j * KK + k0]) = pack;
    }

    red[grp][jg * KK + k0]     = s0;
    red[grp][jg * KK + k0 + 1] = s1;
    __syncthreads();

    // reduce: threads 0..511 -> (row = tid>>7, k = tid&127)
    if (tid < RPB * KK) {
        const int r = tid >> 7;
        const int k = tid & 127;
        const float* rr = red[r];
        sums[r][k] = rr[k] + rr[KK + k] + rr[2 * KK + k] + rr[3 * KK + k];
    }
    __syncthreads();

    // ---- phase D: ONE proj_w pass for 4 rows (threads 0..767 own e=tid) ----
    if (tid < EE) {
        const int e = tid;
        float acc0 = 0.f, acc1 = 0.f, acc2 = 0.f, acc3 = 0.f;
#pragma unroll 8
        for (int k = 0; k < KK; ++k) {
            const float w = proj_w[k * EE + e];
            acc0 += sums[0][k] * w;
            acc1 += sums[1][k] * w;
            acc2 += sums[2][k] * w;
            acc3 += sums[3][k] * w;
        }
        const float pb = proj_b[e];
        const size_t o = (size_t)bi0 * EE;
        out_merge[o + e]          = padr[0] ? 0.0f : (acc0 + pb);
        out_merge[o + EE + e]     = padr[1] ? 0.0f : (acc1 + pb);
        out_merge[o + 2 * EE + e] = padr[2] ? 0.0f : (acc2 + pb);
        out_merge[o + 3 * EE + e] = padr[3] ? 0.0f : (acc3 + pb);
    }
}

extern "C" void kernel_launch(void* const* d_in, const int* in_sizes, int n_in,
                              void* d_out, int out_size, void* d_ws, size_t ws_size,
                              hipStream_t stream) {
    const float* pos          = (const float*)d_in[0];
    const int* node_type_edge = (const int*)d_in[1];
    const int* padding_mask   = (const int*)d_in[2];
    const int* mask_aa        = (const int*)d_in[3];
    const int* mask_pos       = (const int*)d_in[4];
    const int* time_pos       = (const int*)d_in[5];
    const float* means        = (const float*)d_in[6];
    const float* stds         = (const float*)d_in[7];
    const float* mul_w        = (const float*)d_in[8];
    const float* bias_w       = (const float*)d_in[9];
    const float* proj_w       = (const float*)d_in[10];
    const float* proj_b       = (const float*)d_in[11];
    const float* t_w1         = (const float*)d_in[12];
    const float* t_b1         = (const float*)d_in[13];
    const float* t_w2         = (const float*)d_in[14];
    const float* t_b2         = (const float*)d_in[15];

    float* out       = (float*)d_out;
    float* out_ef    = out;                                        // B*N*N*K
    float* out_merge = out + (size_t)BB * NN * NN * KK;            // B*N*E
    float* out_dp    = out_merge + (size_t)BB * NN * EE;           // B*N*N*3

    edge_fused4_kernel<<<(BB * NN) / RPB, 1024, 0, stream>>>(
        pos, node_type_edge, padding_mask, mask_aa, mask_pos, time_pos,
        means, stds, mul_w, bias_w, proj_w, proj_b,
        t_w1, t_b1, t_w2, t_b2,
        out_ef, out_merge, out_dp);
}